// Round 2
// baseline (519.573 us; speedup 1.0000x reference)
//
#include <hip/hip_runtime.h>

#define T_TOK 2048
#define DIM   2048
#define NEXP  8
#define FF    768
#define NGRP  16   // (expert, slot)

typedef unsigned short u16;
typedef __bf16 bf16x8 __attribute__((ext_vector_type(8)));
typedef float  f32x4  __attribute__((ext_vector_type(4)));
typedef u16    u16x8  __attribute__((ext_vector_type(8)));

__device__ __forceinline__ u16 f2bf(float f) {
    union { unsigned int i; float f; } v; v.f = f;
    unsigned int r = v.i + 0x7FFF + ((v.i >> 16) & 1);   // round-to-nearest-even
    return (u16)(r >> 16);
}

// ---------------- Router: scores, top-2, softmax, group counts ----------------
__global__ void router_kernel(const float* __restrict__ x, const float* __restrict__ wr,
                              int* cnt, int* rt_e, float* rt_p) {
    int t = blockIdx.x;
    int lane = threadIdx.x;
    float xv[32];
#pragma unroll
    for (int i = 0; i < 32; i++) xv[i] = x[(size_t)t * DIM + i * 64 + lane];
    float s[NEXP];
#pragma unroll
    for (int e = 0; e < NEXP; e++) {
        float acc = 0.f;
#pragma unroll
        for (int i = 0; i < 32; i++) acc += xv[i] * wr[(size_t)e * DIM + i * 64 + lane];
        for (int off = 32; off; off >>= 1) acc += __shfl_xor(acc, off);
        s[e] = acc;
    }
    if (lane == 0) {
        int bi = 0; float bv = s[0];
        for (int e = 1; e < NEXP; e++) if (s[e] > bv) { bv = s[e]; bi = e; }
        float sv = -1e30f; int si = 0;
        for (int e = 0; e < NEXP; e++) { if (e == bi) continue; if (s[e] > sv) { sv = s[e]; si = e; } }
        float p0 = 1.f / (1.f + __expf(sv - bv));
        float p1 = 1.f - p0;
        rt_e[t * 2 + 0] = bi; rt_e[t * 2 + 1] = si;
        rt_p[t * 2 + 0] = p0; rt_p[t * 2 + 1] = p1;
        atomicAdd(&cnt[bi * 2 + 0], 1);
        atomicAdd(&cnt[si * 2 + 1], 1);
    }
}

// ---------------- Scan: bases + tile worklist ----------------
__global__ void scan_kernel(const int* cnt, int* base, int* tile_g, int* tile_m0, int* ntiles) {
    if (threadIdx.x == 0 && blockIdx.x == 0) {
        int off = 0, nt = 0;
        for (int g = 0; g < NGRP; g++) {
            base[g] = off;
            int c = cnt[g];
            for (int m0 = 0; m0 < c; m0 += 32) { tile_g[nt] = g; tile_m0[nt] = m0; nt++; }
            off += c;
        }
        *ntiles = nt;
    }
}

// ---------------- Assign: compact row -> (token, prob) ----------------
__global__ void assign_kernel(const int* rt_e, const float* rt_p, const int* base,
                              int* poscnt, int* rowtok, float* rowprob) {
    int t = blockIdx.x * blockDim.x + threadIdx.x;
    if (t >= T_TOK) return;
    for (int k = 0; k < 2; k++) {
        int g = rt_e[t * 2 + k] * 2 + k;
        int pos = atomicAdd(&poscnt[g], 1);
        int row = base[g] + pos;
        rowtok[row] = t;
        rowprob[row] = rt_p[t * 2 + k];
    }
}

__device__ __forceinline__ u16x8 pack_bf8(f32x4 a, f32x4 b) {
    u16x8 r;
#pragma unroll
    for (int j = 0; j < 4; j++) { r[j] = f2bf(a[j]); r[4 + j] = f2bf(b[j]); }
    return r;
}

// ---------------- Gate/Up GEMM + SiLU fuse: 32 rows x 64 f per block ----------------
__launch_bounds__(256)
__global__ void gateup_kernel(const float* __restrict__ x, const float* __restrict__ wg,
                              const float* __restrict__ wu,
                              const int* cnt, const int* base, const int* tile_g,
                              const int* tile_m0, const int* ntiles,
                              const int* rowtok, const float* rowprob,
                              u16* __restrict__ hidden) {
    int tile = blockIdx.x;
    if (tile >= *ntiles) return;
    int g = tile_g[tile], m0 = tile_m0[tile];
    int e = g >> 1;
    int f0 = blockIdx.y * 64;
    int cg = cnt[g], bg_ = base[g];

    __shared__ alignas(16) u16 Xs[32 * 40];
    __shared__ alignas(16) u16 Gs[64 * 40];
    __shared__ alignas(16) u16 Us[64 * 40];
    __shared__ int   tks[32];
    __shared__ float ps[32];

    int tid = threadIdx.x;
    if (tid < 32) {
        int valid = (m0 + tid) < cg;
        tks[tid] = valid ? rowtok[bg_ + m0 + tid] : 0;
        ps[tid]  = valid ? rowprob[bg_ + m0 + tid] : 0.f;
    }
    __syncthreads();

    int wave = tid >> 6, lane = tid & 63;
    int quad = lane >> 4, l16 = lane & 15;
    int mbase = (wave & 1) * 16;
    int fbase = (wave >> 1) * 32;

    f32x4 accg[2] = {}, accu[2] = {};

    int sm = tid >> 2;          // 0..63
    int sk = (tid & 3) * 8;     // 0,8,16,24
    int xtok = tks[sm & 31];
    const float* xrow  = x  + (size_t)xtok * DIM + sk;
    const float* wgrow = wg + ((size_t)e * FF + f0 + sm) * DIM + sk;
    const float* wurow = wu + ((size_t)e * FF + f0 + sm) * DIM + sk;

    for (int kk = 0; kk < DIM; kk += 32) {
        f32x4 x0, x1, g0, g1, u0, u1;
        if (tid < 128) { x0 = *(const f32x4*)(xrow + kk); x1 = *(const f32x4*)(xrow + kk + 4); }
        g0 = *(const f32x4*)(wgrow + kk); g1 = *(const f32x4*)(wgrow + kk + 4);
        u0 = *(const f32x4*)(wurow + kk); u1 = *(const f32x4*)(wurow + kk + 4);
        __syncthreads();
        if (tid < 128) *(u16x8*)&Xs[(sm & 31) * 40 + sk] = pack_bf8(x0, x1);
        *(u16x8*)&Gs[sm * 40 + sk] = pack_bf8(g0, g1);
        *(u16x8*)&Us[sm * 40 + sk] = pack_bf8(u0, u1);
        __syncthreads();
        bf16x8 a   = *(const bf16x8*)&Xs[(mbase + l16) * 40 + quad * 8];
        bf16x8 g0v = *(const bf16x8*)&Gs[(fbase + l16) * 40 + quad * 8];
        bf16x8 g1v = *(const bf16x8*)&Gs[(fbase + 16 + l16) * 40 + quad * 8];
        bf16x8 u0v = *(const bf16x8*)&Us[(fbase + l16) * 40 + quad * 8];
        bf16x8 u1v = *(const bf16x8*)&Us[(fbase + 16 + l16) * 40 + quad * 8];
        accg[0] = __builtin_amdgcn_mfma_f32_16x16x32_bf16(a, g0v, accg[0], 0, 0, 0);
        accg[1] = __builtin_amdgcn_mfma_f32_16x16x32_bf16(a, g1v, accg[1], 0, 0, 0);
        accu[0] = __builtin_amdgcn_mfma_f32_16x16x32_bf16(a, u0v, accu[0], 0, 0, 0);
        accu[1] = __builtin_amdgcn_mfma_f32_16x16x32_bf16(a, u1v, accu[1], 0, 0, 0);
    }

#pragma unroll
    for (int c = 0; c < 2; c++) {
#pragma unroll
        for (int r = 0; r < 4; r++) {
            int m = mbase + quad * 4 + r;
            if (m0 + m < cg) {
                float gv = accg[c][r], uv = accu[c][r];
                float h = (gv / (1.f + __expf(-gv))) * uv * ps[m];
                int row = bg_ + m0 + m;
                int f = f0 + fbase + c * 16 + l16;
                hidden[(size_t)row * FF + f] = f2bf(h);
            }
        }
    }
}

// ---------------- Down GEMM: 32 rows x 64 d per block, atomicAdd into out ----------------
__launch_bounds__(256)
__global__ void down_kernel(const u16* __restrict__ hidden, const float* __restrict__ wd,
                            const int* cnt, const int* base, const int* tile_g,
                            const int* tile_m0, const int* ntiles, const int* rowtok,
                            float* __restrict__ out) {
    int tile = blockIdx.x;
    if (tile >= *ntiles) return;
    int g = tile_g[tile], m0 = tile_m0[tile];
    int e = g >> 1;
    int d0 = blockIdx.y * 64;
    int cg = cnt[g], bg_ = base[g];

    __shared__ alignas(16) u16 Hs[32 * 40];
    __shared__ alignas(16) u16 Ws[64 * 40];
    __shared__ int tks[32];

    int tid = threadIdx.x;
    if (tid < 32) tks[tid] = ((m0 + tid) < cg) ? rowtok[bg_ + m0 + tid] : 0;
    __syncthreads();

    int wave = tid >> 6, lane = tid & 63;
    int quad = lane >> 4, l16 = lane & 15;
    int mbase = (wave & 1) * 16;
    int dbase = (wave >> 1) * 32;

    f32x4 acc[2] = {};

    int sm = tid >> 2;
    int sk = (tid & 3) * 8;
    const u16*  hrow = hidden + (size_t)(bg_ + m0 + (sm & 31)) * FF + sk;
    const float* wrow = wd + ((size_t)e * DIM + d0 + sm) * FF + sk;

    for (int kk = 0; kk < FF; kk += 32) {
        u16x8 ha;
        f32x4 w0, w1;
        if (tid < 128) ha = *(const u16x8*)(hrow + kk);
        w0 = *(const f32x4*)(wrow + kk); w1 = *(const f32x4*)(wrow + kk + 4);
        __syncthreads();
        if (tid < 128) *(u16x8*)&Hs[(sm & 31) * 40 + sk] = ha;
        *(u16x8*)&Ws[sm * 40 + sk] = pack_bf8(w0, w1);
        __syncthreads();
        bf16x8 a  = *(const bf16x8*)&Hs[(mbase + l16) * 40 + quad * 8];
        bf16x8 b0 = *(const bf16x8*)&Ws[(dbase + l16) * 40 + quad * 8];
        bf16x8 b1 = *(const bf16x8*)&Ws[(dbase + 16 + l16) * 40 + quad * 8];
        acc[0] = __builtin_amdgcn_mfma_f32_16x16x32_bf16(a, b0, acc[0], 0, 0, 0);
        acc[1] = __builtin_amdgcn_mfma_f32_16x16x32_bf16(a, b1, acc[1], 0, 0, 0);
    }

#pragma unroll
    for (int c = 0; c < 2; c++) {
#pragma unroll
        for (int r = 0; r < 4; r++) {
            int m = mbase + quad * 4 + r;
            if (m0 + m < cg) {
                int t = tks[m];
                int d = d0 + dbase + c * 16 + l16;
                atomicAdd(&out[(size_t)t * DIM + d], acc[c][r]);
            }
        }
    }
}

extern "C" void kernel_launch(void* const* d_in, const int* in_sizes, int n_in,
                              void* d_out, int out_size, void* d_ws, size_t ws_size,
                              hipStream_t stream) {
    const float* x  = (const float*)d_in[0];
    const float* wr = (const float*)d_in[1];
    const float* wg = (const float*)d_in[2];
    const float* wu = (const float*)d_in[3];
    const float* wd = (const float*)d_in[4];
    float* out = (float*)d_out;

    char* W = (char*)d_ws;
    int*   cnt     = (int*)(W + 0);       // 16
    int*   poscnt  = (int*)(W + 64);      // 16
    int*   base    = (int*)(W + 128);     // 16
    int*   ntiles  = (int*)(W + 192);     // 1
    int*   tile_g  = (int*)(W + 1024);    // <=160
    int*   tile_m0 = (int*)(W + 2048);    // <=160
    int*   rt_e    = (int*)(W + 4096);    // 4096 ints
    float* rt_p    = (float*)(W + 4096 + 16384);
    int*   rowtok  = (int*)(W + 40960);   // 4096
    float* rowprob = (float*)(W + 61440);
    u16*   hidden  = (u16*)(W + 81920);   // ~(4096+32) x 768 bf16 ~ 6.34 MB

    hipMemsetAsync(W, 0, 256, stream);                         // cnt, poscnt, base, ntiles
    hipMemsetAsync(d_out, 0, (size_t)out_size * 4, stream);    // accumulate target

    router_kernel<<<T_TOK, 64, 0, stream>>>(x, wr, cnt, rt_e, rt_p);
    scan_kernel<<<1, 64, 0, stream>>>(cnt, base, tile_g, tile_m0, ntiles);
    assign_kernel<<<8, 256, 0, stream>>>(rt_e, rt_p, base, poscnt, rowtok, rowprob);
    gateup_kernel<<<dim3(144, 12), 256, 0, stream>>>(x, wg, wu, cnt, base, tile_g, tile_m0,
                                                     ntiles, rowtok, rowprob, hidden);
    down_kernel<<<dim3(144, 32), 256, 0, stream>>>(hidden, wd, cnt, base, tile_g, tile_m0,
                                                   ntiles, rowtok, out);
}

// Round 3
// 393.975 us; speedup vs baseline: 1.3188x; 1.3188x over previous
//
#include <hip/hip_runtime.h>

#define T_TOK 2048
#define DIM   2048
#define NEXP  8
#define FF    768
#define NGRP  16   // (expert, slot)

typedef unsigned short u16;
typedef unsigned int   u32;
typedef __bf16 bf16x8 __attribute__((ext_vector_type(8)));
typedef float  f32x4  __attribute__((ext_vector_type(4)));
typedef u16    u16x4  __attribute__((ext_vector_type(4)));

#define AS1 __attribute__((address_space(1)))
#define AS3 __attribute__((address_space(3)))

__device__ __forceinline__ u16 f2bf(float f) {
    union { u32 i; float f; } v; v.f = f;
    u32 r = v.i + 0x7FFF + ((v.i >> 16) & 1);   // round-to-nearest-even
    return (u16)(r >> 16);
}

// async global->LDS, 16B per lane; LDS dest = wave-uniform base + lane*16
__device__ __forceinline__ void gload16(const u16* g, u16* l) {
    __builtin_amdgcn_global_load_lds((const AS1 u32*)g, (AS3 u32*)l, 16, 0, 0);
}

// ---------------- fp32 -> bf16 bulk convert ----------------
__global__ void cvt_kernel(const float* __restrict__ s, u16* __restrict__ d, int n4) {
    int i = blockIdx.x * blockDim.x + threadIdx.x;
    int st = gridDim.x * blockDim.x;
    for (; i < n4; i += st) {
        f32x4 v = ((const f32x4*)s)[i];
        u16x4 o;
#pragma unroll
        for (int j = 0; j < 4; j++) o[j] = f2bf(v[j]);
        ((u16x4*)d)[i] = o;
    }
}

// ---------------- Router: scores, top-2, softmax, group counts ----------------
__global__ void router_kernel(const float* __restrict__ x, const float* __restrict__ wr,
                              int* cnt, int* rt_e, float* rt_p) {
    int t = blockIdx.x;
    int lane = threadIdx.x;
    float xv[32];
#pragma unroll
    for (int i = 0; i < 32; i++) xv[i] = x[(size_t)t * DIM + i * 64 + lane];
    float s[NEXP];
#pragma unroll
    for (int e = 0; e < NEXP; e++) {
        float acc = 0.f;
#pragma unroll
        for (int i = 0; i < 32; i++) acc += xv[i] * wr[(size_t)e * DIM + i * 64 + lane];
        for (int off = 32; off; off >>= 1) acc += __shfl_xor(acc, off);
        s[e] = acc;
    }
    if (lane == 0) {
        int bi = 0; float bv = s[0];
        for (int e = 1; e < NEXP; e++) if (s[e] > bv) { bv = s[e]; bi = e; }
        float sv = -1e30f; int si = 0;
        for (int e = 0; e < NEXP; e++) { if (e == bi) continue; if (s[e] > sv) { sv = s[e]; si = e; } }
        float p0 = 1.f / (1.f + __expf(sv - bv));
        float p1 = 1.f - p0;
        rt_e[t * 2 + 0] = bi; rt_e[t * 2 + 1] = si;
        rt_p[t * 2 + 0] = p0; rt_p[t * 2 + 1] = p1;
        atomicAdd(&cnt[bi * 2 + 0], 1);
        atomicAdd(&cnt[si * 2 + 1], 1);
    }
}

// ---------------- Scan: bases + 128-row tile worklist ----------------
__global__ void scan_kernel(const int* cnt, int* base, int* tile_g, int* tile_m0, int* ntiles) {
    if (threadIdx.x == 0 && blockIdx.x == 0) {
        int off = 0, nt = 0;
        for (int g = 0; g < NGRP; g++) {
            base[g] = off;
            int c = cnt[g];
            for (int m0 = 0; m0 < c; m0 += 128) { tile_g[nt] = g; tile_m0[nt] = m0; nt++; }
            off += c;
        }
        *ntiles = nt;
    }
}

// ---------------- Assign: compact row -> (token, prob) ----------------
__global__ void assign_kernel(const int* rt_e, const float* rt_p, const int* base,
                              int* poscnt, int* rowtok, float* rowprob) {
    int t = blockIdx.x * blockDim.x + threadIdx.x;
    if (t >= T_TOK) return;
    for (int k = 0; k < 2; k++) {
        int g = rt_e[t * 2 + k] * 2 + k;
        int pos = atomicAdd(&poscnt[g], 1);
        int row = base[g] + pos;
        rowtok[row] = t;
        rowprob[row] = rt_p[t * 2 + k];
    }
}

// ---------------- Gate/Up GEMM + SiLU: 128 rows x 64 f (N=128 G|U interleaved) ----------------
__launch_bounds__(256)
__global__ void gateup_kernel(const u16* __restrict__ xb, const u16* __restrict__ wgb,
                              const u16* __restrict__ wub,
                              const int* cnt, const int* base, const int* tile_g,
                              const int* tile_m0, const int* ntiles,
                              const int* rowtok, const float* rowprob,
                              u16* __restrict__ hidden) {
    int tile = blockIdx.x;
    if (tile >= *ntiles) return;
    int g = tile_g[tile], m0 = tile_m0[tile];
    int e = g >> 1;
    int f0 = blockIdx.y * 64;
    int cg = cnt[g], bg_ = base[g];

    __shared__ u16 As[128 * 32];
    __shared__ u16 Bs[128 * 32];
    __shared__ int   tks[128];
    __shared__ float ps[128];

    int tid = threadIdx.x;
    if (tid < 128) {
        int valid = (m0 + tid) < cg;
        tks[tid] = valid ? rowtok[bg_ + m0 + tid] : 0;
        ps[tid]  = valid ? rowprob[bg_ + m0 + tid] : 0.f;
    }
    __syncthreads();

    int wave = tid >> 6, lane = tid & 63;
    int quad = lane >> 4, l16 = lane & 15;
    int wr = wave >> 1, wc = wave & 1;

    // staging: wave handles A rows [wave*32, +32) and B rows [wave*32, +32), 2 chunks of 16 rows each
    int r4   = lane >> 2;          // 0..15 row within chunk
    int koff = (lane & 3) * 8;     // element offset within 32-elem k-slab
    int arow0 = wave * 32 + r4;
    const u16* ga0 = xb + (size_t)tks[arow0] * DIM + koff;
    const u16* ga1 = xb + (size_t)tks[arow0 + 16] * DIM + koff;
    // B chunk c (rows [c*16, c*16+16)): is_up = c&1, f = f0 + (c>>1)*16 + r4
    int c0 = wave * 2;
    const u16* wsrc0 = (c0 & 1) ? wub : wgb;
    const u16* wsrc1 = ((c0 + 1) & 1) ? wub : wgb;
    const u16* gb0 = wsrc0 + ((size_t)e * FF + f0 + ((c0) >> 1) * 16 + r4) * DIM + koff;
    const u16* gb1 = wsrc1 + ((size_t)e * FF + f0 + ((c0 + 1) >> 1) * 16 + r4) * DIM + koff;
    u16* lA0 = &As[(wave * 32) * 32];
    u16* lA1 = &As[(wave * 32 + 16) * 32];
    u16* lB0 = &Bs[(c0 * 16) * 32];
    u16* lB1 = &Bs[((c0 + 1) * 16) * 32];

    f32x4 acc[4][4] = {};

    for (int kk = 0; kk < DIM; kk += 32) {
        gload16(ga0 + kk, lA0);
        gload16(ga1 + kk, lA1);
        gload16(gb0 + kk, lB0);
        gload16(gb1 + kk, lB1);
        __syncthreads();
        bf16x8 a[4], b[4];
#pragma unroll
        for (int mi = 0; mi < 4; mi++)
            a[mi] = *(const bf16x8*)&As[(wr * 64 + mi * 16 + l16) * 32 + quad * 8];
#pragma unroll
        for (int ni = 0; ni < 4; ni++)
            b[ni] = *(const bf16x8*)&Bs[(wc * 64 + ni * 16 + l16) * 32 + quad * 8];
#pragma unroll
        for (int mi = 0; mi < 4; mi++)
#pragma unroll
            for (int ni = 0; ni < 4; ni++)
                acc[mi][ni] = __builtin_amdgcn_mfma_f32_16x16x32_bf16(a[mi], b[ni], acc[mi][ni], 0, 0, 0);
        __syncthreads();
    }

    // epilogue: pair gate (ni even) with up (ni+1); f = f0 + (wc*2 + ni/2)*16 + l16
#pragma unroll
    for (int mi = 0; mi < 4; mi++) {
#pragma unroll
        for (int p = 0; p < 2; p++) {
            int f = f0 + (wc * 2 + p) * 16 + l16;
#pragma unroll
            for (int r = 0; r < 4; r++) {
                int m = wr * 64 + mi * 16 + quad * 4 + r;
                if (m0 + m < cg) {
                    float gv = acc[mi][p * 2][r], uv = acc[mi][p * 2 + 1][r];
                    float h = (gv / (1.f + __expf(-gv))) * uv * ps[m];
                    hidden[(size_t)(bg_ + m0 + m) * FF + f] = f2bf(h);
                }
            }
        }
    }
}

// ---------------- Down GEMM: 128 rows x 128 d, atomicAdd into out ----------------
__launch_bounds__(256)
__global__ void down_kernel(const u16* __restrict__ hid, const u16* __restrict__ wdb,
                            const int* cnt, const int* base, const int* tile_g,
                            const int* tile_m0, const int* ntiles, const int* rowtok,
                            float* __restrict__ out) {
    int tile = blockIdx.x;
    if (tile >= *ntiles) return;
    int g = tile_g[tile], m0 = tile_m0[tile];
    int e = g >> 1;
    int d0 = blockIdx.y * 128;
    int cg = cnt[g], bg_ = base[g];

    __shared__ u16 As[128 * 32];
    __shared__ u16 Bs[128 * 32];
    __shared__ int tks[128];

    int tid = threadIdx.x;
    if (tid < 128) tks[tid] = ((m0 + tid) < cg) ? rowtok[bg_ + m0 + tid] : 0;
    __syncthreads();

    int wave = tid >> 6, lane = tid & 63;
    int quad = lane >> 4, l16 = lane & 15;
    int wr = wave >> 1, wc = wave & 1;

    int r4   = lane >> 2;
    int koff = (lane & 3) * 8;
    int arow0 = wave * 32 + r4;
    const u16* ga0 = hid + (size_t)(bg_ + m0 + arow0) * FF + koff;
    const u16* ga1 = hid + (size_t)(bg_ + m0 + arow0 + 16) * FF + koff;
    int c0 = wave * 2;
    const u16* gb0 = wdb + ((size_t)e * DIM + d0 + c0 * 16 + r4) * FF + koff;
    const u16* gb1 = wdb + ((size_t)e * DIM + d0 + (c0 + 1) * 16 + r4) * FF + koff;
    u16* lA0 = &As[(wave * 32) * 32];
    u16* lA1 = &As[(wave * 32 + 16) * 32];
    u16* lB0 = &Bs[(c0 * 16) * 32];
    u16* lB1 = &Bs[((c0 + 1) * 16) * 32];

    f32x4 acc[4][4] = {};

    for (int kk = 0; kk < FF; kk += 32) {
        gload16(ga0 + kk, lA0);
        gload16(ga1 + kk, lA1);
        gload16(gb0 + kk, lB0);
        gload16(gb1 + kk, lB1);
        __syncthreads();
        bf16x8 a[4], b[4];
#pragma unroll
        for (int mi = 0; mi < 4; mi++)
            a[mi] = *(const bf16x8*)&As[(wr * 64 + mi * 16 + l16) * 32 + quad * 8];
#pragma unroll
        for (int ni = 0; ni < 4; ni++)
            b[ni] = *(const bf16x8*)&Bs[(wc * 64 + ni * 16 + l16) * 32 + quad * 8];
#pragma unroll
        for (int mi = 0; mi < 4; mi++)
#pragma unroll
            for (int ni = 0; ni < 4; ni++)
                acc[mi][ni] = __builtin_amdgcn_mfma_f32_16x16x32_bf16(a[mi], b[ni], acc[mi][ni], 0, 0, 0);
        __syncthreads();
    }

#pragma unroll
    for (int mi = 0; mi < 4; mi++) {
#pragma unroll
        for (int ni = 0; ni < 4; ni++) {
            int d = d0 + wc * 64 + ni * 16 + l16;
#pragma unroll
            for (int r = 0; r < 4; r++) {
                int m = wr * 64 + mi * 16 + quad * 4 + r;
                if (m0 + m < cg) {
                    atomicAdd(&out[(size_t)tks[m] * DIM + d], acc[mi][ni][r]);
                }
            }
        }
    }
}

extern "C" void kernel_launch(void* const* d_in, const int* in_sizes, int n_in,
                              void* d_out, int out_size, void* d_ws, size_t ws_size,
                              hipStream_t stream) {
    const float* x  = (const float*)d_in[0];
    const float* wr = (const float*)d_in[1];
    const float* wg = (const float*)d_in[2];
    const float* wu = (const float*)d_in[3];
    const float* wd = (const float*)d_in[4];
    float* out = (float*)d_out;

    char* W = (char*)d_ws;
    int*   cnt     = (int*)(W + 0);
    int*   poscnt  = (int*)(W + 64);
    int*   base    = (int*)(W + 128);
    int*   ntiles  = (int*)(W + 192);
    int*   tile_g  = (int*)(W + 256);           // <=48
    int*   tile_m0 = (int*)(W + 512);           // <=48
    int*   rt_e    = (int*)(W + 1024);          // 4096 ints
    float* rt_p    = (float*)(W + 20480);
    int*   rowtok  = (int*)(W + 40960);
    float* rowprob = (float*)(W + 61440);
    u16*   hidden  = (u16*)(W + 81920);         // (4096+128) x 768 bf16 ~ 6.49 MB
    u16*   xb      = (u16*)(W + ((size_t)8  << 20));   // 8.39 MB
    u16*   wgb     = (u16*)(W + ((size_t)17 << 20));   // 25.2 MB
    u16*   wub     = (u16*)(W + ((size_t)43 << 20));   // 25.2 MB
    u16*   wdb     = (u16*)(W + ((size_t)69 << 20));   // 25.2 MB  (end ~94.4 MB)

    hipMemsetAsync(W, 0, 256, stream);                       // cnt, poscnt, base, ntiles
    hipMemsetAsync(d_out, 0, (size_t)out_size * 4, stream);  // accumulate target

    const int NW = NEXP * FF * DIM / 4;   // 3.15M float4 per weight tensor
    const int NX = T_TOK * DIM / 4;
    cvt_kernel<<<1280, 256, 0, stream>>>(x,  xb,  NX);
    cvt_kernel<<<1280, 256, 0, stream>>>(wg, wgb, NW);
    cvt_kernel<<<1280, 256, 0, stream>>>(wu, wub, NW);
    cvt_kernel<<<1280, 256, 0, stream>>>(wd, wdb, NW);

    router_kernel<<<T_TOK, 64, 0, stream>>>(x, wr, cnt, rt_e, rt_p);
    scan_kernel<<<1, 64, 0, stream>>>(cnt, base, tile_g, tile_m0, ntiles);
    assign_kernel<<<8, 256, 0, stream>>>(rt_e, rt_p, base, poscnt, rowtok, rowprob);

    gateup_kernel<<<dim3(48, 12), 256, 0, stream>>>(xb, wgb, wub, cnt, base, tile_g, tile_m0,
                                                    ntiles, rowtok, rowprob, hidden);
    down_kernel<<<dim3(48, 16), 256, 0, stream>>>(hidden, wdb, cnt, base, tile_g, tile_m0,
                                                  ntiles, rowtok, out);
}